// Round 7
// baseline (219.335 us; speedup 1.0000x reference)
//
#include <hip/hip_runtime.h>
#include <hip/hip_bf16.h>

// Problem constants: B=2, T=2048, C=1024, H=16, D=64
#define Bq 2
#define Tq 2048
#define Cq 1024
#define Hq 16
#define Dq 64
#define Mq (Bq * Tq)  // 4096 rows

typedef __bf16 bf16x8 __attribute__((ext_vector_type(8)));
typedef float f32x4 __attribute__((ext_vector_type(4)));
typedef unsigned uint4v __attribute__((ext_vector_type(4)));
typedef unsigned short u16;

static __device__ __forceinline__ u16 f2bf(float f) {
  union { float f; unsigned u; } v; v.f = f;
  return (u16)((v.u + 0x7fffu + ((v.u >> 16) & 1u)) >> 16);
}

static __device__ __forceinline__ unsigned cvt_pk_bf16(float a, float b) {
  unsigned r;
  asm("v_cvt_pk_bf16_f32 %0, %1, %2" : "=v"(r) : "v"(a), "v"(b));
  return r;  // lo = bf16(a), hi = bf16(b), RNE
}

static __device__ __forceinline__ f32x4 mfma16(bf16x8 a, bf16x8 b, f32x4 c) {
  return __builtin_amdgcn_mfma_f32_16x16x32_bf16(a, b, c, 0, 0, 0);
}

// async global->LDS, 16B per lane. LDS dest = wave-uniform base + lane*16.
#define GLD16(g, l)                                                   \
  __builtin_amdgcn_global_load_lds(                                   \
      (const __attribute__((address_space(1))) unsigned int*)(g),     \
      (__attribute__((address_space(3))) unsigned int*)(l), 16, 0, 0)

// s-permutation: k = [ct1 ct0 qd1 qd0 r1 r0] -> s = [ct1 qd1 qd0 ct0 r1 r0].
// Makes MFMA depth slot s = h*32 + l4*8 + j correspond to k = (2h+jh)*16 +
// l4*4 + r, i.e. P's A-operand fragment is lane-local (zero shuffles).
static __device__ __forceinline__ int sperm(int k) {
  return (k & 0x23) | ((k & 0x0C) << 1) | ((k & 0x10) >> 2);
}

// ---------------------------------------------------------------------------
// Pre-pass A: x fp32 -> bf16 (4M elements)
// ---------------------------------------------------------------------------
__global__ __launch_bounds__(256) void convert_x(const float* __restrict__ x,
                                                 u16* __restrict__ xb) {
  int i = (blockIdx.x * 256 + threadIdx.x) * 8;
  float4 a = *(const float4*)(x + i);
  float4 b = *(const float4*)(x + i + 4);
  u16 tmp[8];
  tmp[0] = f2bf(a.x); tmp[1] = f2bf(a.y); tmp[2] = f2bf(a.z); tmp[3] = f2bf(a.w);
  tmp[4] = f2bf(b.x); tmp[5] = f2bf(b.y); tmp[6] = f2bf(b.z); tmp[7] = f2bf(b.w);
  *(uint4*)(xb + i) = *(const uint4*)tmp;
}

// ---------------------------------------------------------------------------
// Pre-pass B: W fp32 [K][N] -> Wt bf16 [N][K] (tiled transpose via LDS)
// ---------------------------------------------------------------------------
__global__ __launch_bounds__(256) void transpose_w(const float* __restrict__ W,
                                                   u16* __restrict__ Wt,
                                                   int K, int N) {
  __shared__ __align__(16) u16 Ts[64][72];  // [n][k]
  const int k0 = blockIdx.x * 64, n0 = blockIdx.y * 64;
  const int t = threadIdx.x;
  const int r = t >> 2, c0 = (t & 3) * 16;
  const float* src = W + (size_t)(k0 + r) * N + n0 + c0;
  u16 v16[16];
#pragma unroll
  for (int i = 0; i < 4; i++) {
    float4 f = *(const float4*)(src + 4 * i);
    v16[4 * i + 0] = f2bf(f.x); v16[4 * i + 1] = f2bf(f.y);
    v16[4 * i + 2] = f2bf(f.z); v16[4 * i + 3] = f2bf(f.w);
  }
#pragma unroll
  for (int j = 0; j < 16; j++) Ts[c0 + j][r] = v16[j];
  __syncthreads();
  u16* dst = Wt + (size_t)(n0 + r) * K + k0 + c0;
  *(uint4*)dst = *(const uint4*)&Ts[r][c0];
  *(uint4*)(dst + 8) = *(const uint4*)&Ts[r][c0 + 8];
}

// ---------------------------------------------------------------------------
// Pre-pass C: V [B,H,T,D] bf16 -> V^T [B,H,D,T] bf16 with s-permuted columns
// within each 64-aligned t-tile (so attn's B-operand reads are contiguous).
// ---------------------------------------------------------------------------
__global__ __launch_bounds__(256) void transpose_v(const u16* __restrict__ vw,
                                                   u16* __restrict__ vts) {
  __shared__ __align__(16) u16 Ts[64][72];  // [d][s]
  const int tile = blockIdx.x, bh = blockIdx.y;
  const size_t base = (size_t)bh * Tq * Dq;
  const int t = threadIdx.x;
  const int rv = t >> 2, c0 = (t & 3) * 16;
  const u16* src = vw + base + (size_t)(tile * 64 + rv) * Dq + c0;
  union { uint4 q[2]; u16 s[16]; } vu;
  vu.q[0] = *(const uint4*)src;
  vu.q[1] = *(const uint4*)(src + 8);
  const int sc = sperm(rv);
#pragma unroll
  for (int j = 0; j < 16; j++) Ts[c0 + j][sc] = vu.s[j];
  __syncthreads();
  u16* dst = vts + base + (size_t)rv * Tq + tile * 64 + c0;
  *(uint4*)dst = *(const uint4*)&Ts[rv][c0];
  *(uint4*)(dst + 8) = *(const uint4*)&Ts[rv][c0 + 8];
}

// ---------------------------------------------------------------------------
// Kernel 1: QKV = xb @ Wt^T + b, scatter to Q/K/V [B,H,T,D] bf16.
// Q pre-scaled by 0.125*log2(e). `which` is uniform per block (n0 128-aligned).
// ---------------------------------------------------------------------------
__global__ __launch_bounds__(256) void qkv_gemm(
    const u16* __restrict__ A, const u16* __restrict__ Bt,
    const float* __restrict__ bias,
    u16* __restrict__ qw, u16* __restrict__ kw, u16* __restrict__ vw) {
  const int K = 1024;
  __shared__ __align__(16) u16 As[128][32];
  __shared__ __align__(16) u16 Bs[128][32];
  const int m0 = blockIdx.x * 128, n0 = blockIdx.y * 128;
  const int t = threadIdx.x, lane = t & 63, w = t >> 6;
  const int wm = (w >> 1) * 64, wn = (w & 1) * 64;
  const int l15 = lane & 15, l4 = lane >> 4;
  const int lr = lane >> 2, lc = (lane & 3) * 8;
  f32x4 acc[4][4] = {};
  const u16* ga = A + (size_t)(m0 + w * 16 + lr) * K + lc;
  const u16* gb = Bt + (size_t)(n0 + w * 16 + lr) * K + lc;

  for (int kk = 0; kk < K; kk += 32) {
    __syncthreads();
    GLD16(ga + kk, &As[w * 16][0]);
    GLD16(ga + (size_t)64 * K + kk, &As[64 + w * 16][0]);
    GLD16(gb + kk, &Bs[w * 16][0]);
    GLD16(gb + (size_t)64 * K + kk, &Bs[64 + w * 16][0]);
    __syncthreads();
    bf16x8 af[4], bfr[4];
#pragma unroll
    for (int i = 0; i < 4; i++) {
      af[i] = *(const bf16x8*)&As[wm + i * 16 + l15][l4 * 8];
      bfr[i] = *(const bf16x8*)&Bs[wn + i * 16 + l15][l4 * 8];
    }
#pragma unroll
    for (int mi = 0; mi < 4; mi++)
#pragma unroll
      for (int ni = 0; ni < 4; ni++)
        acc[mi][ni] = mfma16(af[mi], bfr[ni], acc[mi][ni]);
  }
  // epilogue: C frag row=(l>>4)*4+r, col=l&15; block-uniform q/k/v select
  const int which = n0 >> 10;
  u16* dst = (which == 0) ? qw : ((which == 1) ? kw : vw);
  const float qsc = (which == 0) ? 0.18033688011112042f : 1.0f;
#pragma unroll
  for (int mi = 0; mi < 4; mi++) {
#pragma unroll
    for (int ni = 0; ni < 4; ni++) {
#pragma unroll
      for (int r = 0; r < 4; r++) {
        int row = m0 + wm + mi * 16 + l4 * 4 + r;
        int col = n0 + wn + ni * 16 + l15;
        float val = (acc[mi][ni][r] + bias[col]) * qsc;
        int c = col & 1023;
        int h = c >> 6, d = c & 63;
        int b = row >> 11, tt = row & 2047;
        dst[(size_t)((b * Hq + h) * Tq + tt) * Dq + d] = f2bf(val);
      }
    }
  }
}

// ---------------------------------------------------------------------------
// Kernel 2: causal flash attention v6.
// 256 thr = 4 waves x 2 strips; block = 128 q-rows. K and V^T(s-ordered)
// staged via global_load_lds into double-buffered linear [64][64] LDS with
// XOR-pre-swizzled SOURCE addresses (reads granule^(row&7): conflict-free).
// One barrier per tile. P never moves: lane-local cvt_pk pack (rho-trick).
// ---------------------------------------------------------------------------
__global__ __launch_bounds__(256, 2) void attn(
    const u16* __restrict__ qw, const u16* __restrict__ kw,
    const u16* __restrict__ vts, u16* __restrict__ yw) {
  const int bh = blockIdx.x;                 // 32
  const int qy = blockIdx.y;                 // 16
  const int qb = (qy < 8) ? (15 - qy) : (qy - 8);  // heavy+light pairing
  __shared__ __align__(16) u16 Ks[2][64][64];
  __shared__ __align__(16) u16 Vt[2][64][64];
  const int t = threadIdx.x, lane = t & 63, w = t >> 6;
  const int l15 = lane & 15, l4 = lane >> 4;
  const size_t base = (size_t)bh * Tq * Dq;
  const int qs0 = qb * 128 + w * 32;         // strip-0 base (strip1 = +16)

  // Q fragments (B-operand) per strip
  bf16x8 qf[2][2];
  {
    const u16* qp = qw + base + (size_t)(qs0 + l15) * Dq + l4 * 8;
    qf[0][0] = *(const bf16x8*)qp;
    qf[0][1] = *(const bf16x8*)(qp + 32);
    qf[1][0] = *(const bf16x8*)(qp + 16 * Dq);
    qf[1][1] = *(const bf16x8*)(qp + 16 * Dq + 32);
  }

  // staging: wave w covers rows [w*8, w*8+8) and +32; source pre-swizzled
  const int r0 = w * 8 + (lane >> 3);        // 0..31
  const int c0 = ((lane & 7) ^ (r0 & 7)) * 8;
  const u16* kbase = kw + base;
  const u16* vbase = vts + base;

#define STAGE(kv_, b_)                                                      \
  do {                                                                      \
    GLD16(kbase + (size_t)((kv_)*64 + r0) * Dq + c0, &Ks[b_][w * 8][0]);    \
    GLD16(kbase + (size_t)((kv_)*64 + 32 + r0) * Dq + c0,                   \
          &Ks[b_][32 + w * 8][0]);                                          \
    GLD16(vbase + (size_t)r0 * Tq + (kv_)*64 + c0, &Vt[b_][w * 8][0]);      \
    GLD16(vbase + (size_t)(32 + r0) * Tq + (kv_)*64 + c0,                   \
          &Vt[b_][32 + w * 8][0]);                                          \
  } while (0)

  float m[2] = {-1e30f, -1e30f}, lsum[2] = {0.f, 0.f};
  f32x4 accO[2][4] = {};
  const int kvmax = 2 * qb + 1;

  STAGE(0, 0);
  __syncthreads();

  for (int kv = 0; kv <= kvmax; kv++) {
    const int cur = kv & 1;
    if (kv < kvmax) STAGE(kv + 1, cur ^ 1);  // in flight across compute

    if (kv * 64 <= qs0 + 31) {
      // swapped QK^T: sc[s][ct][r] = S[k = kv*64+ct*16+l4*4+r][q = qs+l15]
      f32x4 sc[2][4];
      __builtin_amdgcn_s_setprio(1);
#pragma unroll
      for (int ct = 0; ct < 4; ct++) {
        const int kr = ct * 16 + l15, e = l15 & 7;
        bf16x8 kf0 = *(const bf16x8*)&Ks[cur][kr][8 * (l4 ^ e)];
        bf16x8 kf1 = *(const bf16x8*)&Ks[cur][kr][8 * ((4 + l4) ^ e)];
        f32x4 z0 = {};
        z0 = mfma16(kf0, qf[0][0], z0); z0 = mfma16(kf1, qf[0][1], z0);
        sc[0][ct] = z0;
        f32x4 z1 = {};
        z1 = mfma16(kf0, qf[1][0], z1); z1 = mfma16(kf1, qf[1][1], z1);
        sc[1][ct] = z1;
      }
      __builtin_amdgcn_s_setprio(0);

      if (kv * 64 + 63 > qs0) {  // diagonal region: causal mask
#pragma unroll
        for (int s = 0; s < 2; s++) {
          const int q = qs0 + s * 16 + l15;
#pragma unroll
          for (int ct = 0; ct < 4; ct++)
#pragma unroll
            for (int r = 0; r < 4; r++) {
              int k = kv * 64 + ct * 16 + l4 * 4 + r;
              if (k > q) sc[s][ct][r] = -1e30f;
            }
        }
      }

      // per-strip online softmax + lane-local pack (rho-trick)
      bf16x8 pa[2][2];
#pragma unroll
      for (int s = 0; s < 2; s++) {
        float pmax = sc[s][0][0];
#pragma unroll
        for (int ct = 0; ct < 4; ct++)
#pragma unroll
          for (int r = 0; r < 4; r++) pmax = fmaxf(pmax, sc[s][ct][r]);
        pmax = fmaxf(pmax, __shfl_xor(pmax, 16));
        pmax = fmaxf(pmax, __shfl_xor(pmax, 32));

        if (__any(pmax > m[s] + 8.f)) {  // defer-max (T13)
          float mn = fmaxf(m[s], pmax);
          float corr = exp2f(m[s] - mn);
          m[s] = mn;
          lsum[s] *= corr;
#pragma unroll
          for (int r = 0; r < 4; r++) {  // corr for q=l4*4+r at lane 20*l4+r
            float cb = __shfl(corr, (lane >> 4) * 20 + r);
#pragma unroll
            for (int dt = 0; dt < 4; dt++) accO[s][dt][r] *= cb;
          }
        }

        float psum = 0.f;
#pragma unroll
        for (int ct = 0; ct < 4; ct++)
#pragma unroll
          for (int r = 0; r < 4; r++) {
            float p = exp2f(sc[s][ct][r] - m[s]);
            sc[s][ct][r] = p;
            psum += p;
          }
        psum += __shfl_xor(psum, 16);
        psum += __shfl_xor(psum, 32);
        lsum[s] += psum;

        // pa[h] elements j: j<4 -> sc[2h][j], j>=4 -> sc[2h+1][j-4]
#pragma unroll
        for (int h = 0; h < 2; h++) {
          uint4v pu;
          pu[0] = cvt_pk_bf16(sc[s][2 * h][0], sc[s][2 * h][1]);
          pu[1] = cvt_pk_bf16(sc[s][2 * h][2], sc[s][2 * h][3]);
          pu[2] = cvt_pk_bf16(sc[s][2 * h + 1][0], sc[s][2 * h + 1][1]);
          pu[3] = cvt_pk_bf16(sc[s][2 * h + 1][2], sc[s][2 * h + 1][3]);
          pa[s][h] = __builtin_bit_cast(bf16x8, pu);
        }
      }

      // PV: vf[h] = s-slots h*32 + l4*8 + j at row d (granule ^ (row&7))
      __builtin_amdgcn_s_setprio(1);
#pragma unroll
      for (int dt = 0; dt < 4; dt++) {
        const int Rv = dt * 16 + l15, e = l15 & 7;
        bf16x8 vf0 = *(const bf16x8*)&Vt[cur][Rv][8 * (l4 ^ e)];
        bf16x8 vf1 = *(const bf16x8*)&Vt[cur][Rv][8 * ((4 + l4) ^ e)];
        accO[0][dt] = mfma16(pa[0][0], vf0, accO[0][dt]);
        accO[0][dt] = mfma16(pa[0][1], vf1, accO[0][dt]);
        accO[1][dt] = mfma16(pa[1][0], vf0, accO[1][dt]);
        accO[1][dt] = mfma16(pa[1][1], vf1, accO[1][dt]);
      }
      __builtin_amdgcn_s_setprio(0);
    }
    __syncthreads();  // drains gld (vmcnt) + covers dbuf rotation
  }
#undef STAGE

  // epilogue: O rows q = l4*4+r; inv for that q lives at lane 20*l4+r
  const int b = bh >> 4, hd = bh & 15;
#pragma unroll
  for (int s = 0; s < 2; s++) {
    float inv = 1.0f / lsum[s];
#pragma unroll
    for (int r = 0; r < 4; r++) {
      float ib = __shfl(inv, (lane >> 4) * 20 + r);
      int tt = qs0 + s * 16 + l4 * 4 + r;
      size_t rowbase = ((size_t)(b * Tq + tt)) * Cq + hd * 64;
#pragma unroll
      for (int dt = 0; dt < 4; dt++)
        yw[rowbase + dt * 16 + l15] = f2bf(accO[s][dt][r] * ib);
    }
  }
}

// ---------------------------------------------------------------------------
// Kernel 3: out = y @ Wt_proj^T + b_proj (fp32 out). m97 structure.
// ---------------------------------------------------------------------------
__global__ __launch_bounds__(256) void proj_gemm(
    const u16* __restrict__ A, const u16* __restrict__ Bt,
    const float* __restrict__ bias, float* __restrict__ out) {
  const int K = 1024, N = 1024;
  __shared__ __align__(16) u16 As[128][32];
  __shared__ __align__(16) u16 Bs[128][32];
  const int m0 = blockIdx.x * 128, n0 = blockIdx.y * 128;
  const int t = threadIdx.x, lane = t & 63, w = t >> 6;
  const int wm = (w >> 1) * 64, wn = (w & 1) * 64;
  const int l15 = lane & 15, l4 = lane >> 4;
  const int lr = lane >> 2, lc = (lane & 3) * 8;
  f32x4 acc[4][4] = {};
  const u16* ga = A + (size_t)(m0 + w * 16 + lr) * K + lc;
  const u16* gb = Bt + (size_t)(n0 + w * 16 + lr) * K + lc;

  for (int kk = 0; kk < K; kk += 32) {
    __syncthreads();
    GLD16(ga + kk, &As[w * 16][0]);
    GLD16(ga + (size_t)64 * K + kk, &As[64 + w * 16][0]);
    GLD16(gb + kk, &Bs[w * 16][0]);
    GLD16(gb + (size_t)64 * K + kk, &Bs[64 + w * 16][0]);
    __syncthreads();
    bf16x8 af[4], bfr[4];
#pragma unroll
    for (int i = 0; i < 4; i++) {
      af[i] = *(const bf16x8*)&As[wm + i * 16 + l15][l4 * 8];
      bfr[i] = *(const bf16x8*)&Bs[wn + i * 16 + l15][l4 * 8];
    }
#pragma unroll
    for (int mi = 0; mi < 4; mi++)
#pragma unroll
      for (int ni = 0; ni < 4; ni++)
        acc[mi][ni] = mfma16(af[mi], bfr[ni], acc[mi][ni]);
  }
#pragma unroll
  for (int mi = 0; mi < 4; mi++) {
#pragma unroll
    for (int ni = 0; ni < 4; ni++) {
#pragma unroll
      for (int r = 0; r < 4; r++) {
        int row = m0 + wm + mi * 16 + l4 * 4 + r;
        int col = n0 + wn + ni * 16 + l15;
        out[(size_t)row * N + col] = acc[mi][ni][r] + bias[col];
      }
    }
  }
}

// ---------------------------------------------------------------------------
// Workspace (u16 elems): qw 4M | kw 4M | vw 4M (-> yw after transpose_v) |
// xb 4M (-> vts after qkv_gemm) | wt 3M. Total 38 MB.
// ---------------------------------------------------------------------------
extern "C" void kernel_launch(void* const* d_in, const int* in_sizes, int n_in,
                              void* d_out, int out_size, void* d_ws, size_t ws_size,
                              hipStream_t stream) {
  const float* x = (const float*)d_in[0];
  const float* W_qkv = (const float*)d_in[1];
  const float* b_qkv = (const float*)d_in[2];
  const float* W_proj = (const float*)d_in[3];
  const float* b_proj = (const float*)d_in[4];
  float* out = (float*)d_out;

  const size_t qkv_elems = (size_t)Bq * Hq * Tq * Dq;  // 4M
  u16* qw = (u16*)d_ws;
  u16* kw = qw + qkv_elems;
  u16* vw = kw + qkv_elems;
  u16* xb = vw + qkv_elems;
  u16* wt = xb + (size_t)Mq * Cq;
  u16* vts = xb;  // xb dead after qkv_gemm
  u16* yw = vw;   // vw dead after transpose_v

  convert_x<<<dim3((Mq * Cq) / (256 * 8)), 256, 0, stream>>>(x, xb);
  transpose_w<<<dim3(Cq / 64, 3 * Cq / 64), 256, 0, stream>>>(W_qkv, wt, Cq, 3 * Cq);
  qkv_gemm<<<dim3(Mq / 128, 3 * Cq / 128), 256, 0, stream>>>(xb, wt, b_qkv, qw, kw, vw);
  transpose_v<<<dim3(Tq / 64, Bq * Hq), 256, 0, stream>>>(vw, vts);
  transpose_w<<<dim3(Cq / 64, Cq / 64), 256, 0, stream>>>(W_proj, wt, Cq, Cq);
  attn<<<dim3(Bq * Hq, Tq / 128), 256, 0, stream>>>(qw, kw, vts, yw);
  proj_gemm<<<dim3(Mq / 128, Cq / 128), 256, 0, stream>>>(yw, wt, b_proj, out);
}

// Round 8
// 215.090 us; speedup vs baseline: 1.0197x; 1.0197x over previous
//
#include <hip/hip_runtime.h>
#include <hip/hip_bf16.h>

// Problem constants: B=2, T=2048, C=1024, H=16, D=64
#define Bq 2
#define Tq 2048
#define Cq 1024
#define Hq 16
#define Dq 64
#define Mq (Bq * Tq)  // 4096 rows

typedef __bf16 bf16x8 __attribute__((ext_vector_type(8)));
typedef float f32x4 __attribute__((ext_vector_type(4)));
typedef unsigned uint4v __attribute__((ext_vector_type(4)));
typedef unsigned short u16;

static __device__ __forceinline__ u16 f2bf(float f) {
  union { float f; unsigned u; } v; v.f = f;
  return (u16)((v.u + 0x7fffu + ((v.u >> 16) & 1u)) >> 16);
}

static __device__ __forceinline__ unsigned cvt_pk_bf16(float a, float b) {
  unsigned r;
  asm("v_cvt_pk_bf16_f32 %0, %1, %2" : "=v"(r) : "v"(a), "v"(b));
  return r;  // lo = bf16(a), hi = bf16(b), RNE
}

static __device__ __forceinline__ f32x4 mfma16(bf16x8 a, bf16x8 b, f32x4 c) {
  return __builtin_amdgcn_mfma_f32_16x16x32_bf16(a, b, c, 0, 0, 0);
}

// async global->LDS, 16B per lane. LDS dest = wave-uniform base + lane*16.
#define GLD16(g, l)                                                   \
  __builtin_amdgcn_global_load_lds(                                   \
      (const __attribute__((address_space(1))) unsigned int*)(g),     \
      (__attribute__((address_space(3))) unsigned int*)(l), 16, 0, 0)

// s-permutation: k = [ct1 ct0 qd1 qd0 r1 r0] -> s = [ct1 qd1 qd0 ct0 r1 r0].
// Makes MFMA depth slot s = h*32 + l4*8 + j correspond to k = (2h+jh)*16 +
// l4*4 + r, i.e. P's A-operand fragment is lane-local (zero shuffles).
static __device__ __forceinline__ int sperm(int k) {
  return (k & 0x23) | ((k & 0x0C) << 1) | ((k & 0x10) >> 2);
}

// ---------------------------------------------------------------------------
// Pre-pass A: x fp32 -> bf16 (4M elements)
// ---------------------------------------------------------------------------
__global__ __launch_bounds__(256) void convert_x(const float* __restrict__ x,
                                                 u16* __restrict__ xb) {
  int i = (blockIdx.x * 256 + threadIdx.x) * 8;
  float4 a = *(const float4*)(x + i);
  float4 b = *(const float4*)(x + i + 4);
  u16 tmp[8];
  tmp[0] = f2bf(a.x); tmp[1] = f2bf(a.y); tmp[2] = f2bf(a.z); tmp[3] = f2bf(a.w);
  tmp[4] = f2bf(b.x); tmp[5] = f2bf(b.y); tmp[6] = f2bf(b.z); tmp[7] = f2bf(b.w);
  *(uint4*)(xb + i) = *(const uint4*)tmp;
}

// ---------------------------------------------------------------------------
// Pre-pass B: W fp32 [K][N] -> Wt bf16 [N][K] (tiled transpose via LDS)
// ---------------------------------------------------------------------------
__global__ __launch_bounds__(256) void transpose_w(const float* __restrict__ W,
                                                   u16* __restrict__ Wt,
                                                   int K, int N) {
  __shared__ __align__(16) u16 Ts[64][72];  // [n][k]
  const int k0 = blockIdx.x * 64, n0 = blockIdx.y * 64;
  const int t = threadIdx.x;
  const int r = t >> 2, c0 = (t & 3) * 16;
  const float* src = W + (size_t)(k0 + r) * N + n0 + c0;
  u16 v16[16];
#pragma unroll
  for (int i = 0; i < 4; i++) {
    float4 f = *(const float4*)(src + 4 * i);
    v16[4 * i + 0] = f2bf(f.x); v16[4 * i + 1] = f2bf(f.y);
    v16[4 * i + 2] = f2bf(f.z); v16[4 * i + 3] = f2bf(f.w);
  }
#pragma unroll
  for (int j = 0; j < 16; j++) Ts[c0 + j][r] = v16[j];
  __syncthreads();
  u16* dst = Wt + (size_t)(n0 + r) * K + k0 + c0;
  *(uint4*)dst = *(const uint4*)&Ts[r][c0];
  *(uint4*)(dst + 8) = *(const uint4*)&Ts[r][c0 + 8];
}

// ---------------------------------------------------------------------------
// Pre-pass C: V [B,H,T,D] bf16 -> V^T [B,H,D,T] bf16 with s-permuted columns
// within each 64-aligned t-tile (so attn's B-operand reads are contiguous).
// ---------------------------------------------------------------------------
__global__ __launch_bounds__(256) void transpose_v(const u16* __restrict__ vw,
                                                   u16* __restrict__ vts) {
  __shared__ __align__(16) u16 Ts[64][72];  // [d][s]
  const int tile = blockIdx.x, bh = blockIdx.y;
  const size_t base = (size_t)bh * Tq * Dq;
  const int t = threadIdx.x;
  const int rv = t >> 2, c0 = (t & 3) * 16;
  const u16* src = vw + base + (size_t)(tile * 64 + rv) * Dq + c0;
  union { uint4 q[2]; u16 s[16]; } vu;
  vu.q[0] = *(const uint4*)src;
  vu.q[1] = *(const uint4*)(src + 8);
  const int sc = sperm(rv);
#pragma unroll
  for (int j = 0; j < 16; j++) Ts[c0 + j][sc] = vu.s[j];
  __syncthreads();
  u16* dst = vts + base + (size_t)rv * Tq + tile * 64 + c0;
  *(uint4*)dst = *(const uint4*)&Ts[rv][c0];
  *(uint4*)(dst + 8) = *(const uint4*)&Ts[rv][c0 + 8];
}

// ---------------------------------------------------------------------------
// Kernel 1: QKV = xb @ Wt^T + b, scatter to Q/K/V [B,H,T,D] bf16.
// Q pre-scaled by 0.125*log2(e). `which` is uniform per block (n0 128-aligned).
// ---------------------------------------------------------------------------
__global__ __launch_bounds__(256) void qkv_gemm(
    const u16* __restrict__ A, const u16* __restrict__ Bt,
    const float* __restrict__ bias,
    u16* __restrict__ qw, u16* __restrict__ kw, u16* __restrict__ vw) {
  const int K = 1024;
  __shared__ __align__(16) u16 As[128][32];
  __shared__ __align__(16) u16 Bs[128][32];
  const int m0 = blockIdx.x * 128, n0 = blockIdx.y * 128;
  const int t = threadIdx.x, lane = t & 63, w = t >> 6;
  const int wm = (w >> 1) * 64, wn = (w & 1) * 64;
  const int l15 = lane & 15, l4 = lane >> 4;
  const int lr = lane >> 2, lc = (lane & 3) * 8;
  f32x4 acc[4][4] = {};
  const u16* ga = A + (size_t)(m0 + w * 16 + lr) * K + lc;
  const u16* gb = Bt + (size_t)(n0 + w * 16 + lr) * K + lc;

  for (int kk = 0; kk < K; kk += 32) {
    __syncthreads();
    GLD16(ga + kk, &As[w * 16][0]);
    GLD16(ga + (size_t)64 * K + kk, &As[64 + w * 16][0]);
    GLD16(gb + kk, &Bs[w * 16][0]);
    GLD16(gb + (size_t)64 * K + kk, &Bs[64 + w * 16][0]);
    __syncthreads();
    bf16x8 af[4], bfr[4];
#pragma unroll
    for (int i = 0; i < 4; i++) {
      af[i] = *(const bf16x8*)&As[wm + i * 16 + l15][l4 * 8];
      bfr[i] = *(const bf16x8*)&Bs[wn + i * 16 + l15][l4 * 8];
    }
#pragma unroll
    for (int mi = 0; mi < 4; mi++)
#pragma unroll
      for (int ni = 0; ni < 4; ni++)
        acc[mi][ni] = mfma16(af[mi], bfr[ni], acc[mi][ni]);
  }
  // epilogue: C frag row=(l>>4)*4+r, col=l&15; block-uniform q/k/v select
  const int which = n0 >> 10;
  u16* dst = (which == 0) ? qw : ((which == 1) ? kw : vw);
  const float qsc = (which == 0) ? 0.18033688011112042f : 1.0f;
#pragma unroll
  for (int mi = 0; mi < 4; mi++) {
#pragma unroll
    for (int ni = 0; ni < 4; ni++) {
#pragma unroll
      for (int r = 0; r < 4; r++) {
        int row = m0 + wm + mi * 16 + l4 * 4 + r;
        int col = n0 + wn + ni * 16 + l15;
        float val = (acc[mi][ni][r] + bias[col]) * qsc;
        int c = col & 1023;
        int h = c >> 6, d = c & 63;
        int b = row >> 11, tt = row & 2047;
        dst[(size_t)((b * Hq + h) * Tq + tt) * Dq + d] = f2bf(val);
      }
    }
  }
}

// ---------------------------------------------------------------------------
// Kernel 2: causal flash attention v7 — KVBLK=128.
// 256 thr = 4 waves x 2 strips; block = 128 q-rows. Per 128-k tile:
// 8 ct sub-tiles (QK) / 4 halves (PV), guarded by wave-uniform compile-time-
// unrolled bounds so diagonal tiles skip masked sub-tiles. One barrier per
// 128-k tile. lsum kept as per-lane partials until the epilogue; cross-lane
// max shfls only inside the (rare) rescale branch.
// ---------------------------------------------------------------------------
__global__ __launch_bounds__(256, 2) void attn(
    const u16* __restrict__ qw, const u16* __restrict__ kw,
    const u16* __restrict__ vts, u16* __restrict__ yw) {
  const int bh = blockIdx.x;                 // 32
  const int qy = blockIdx.y;                 // 16
  const int qb = (qy < 8) ? (15 - qy) : (qy - 8);  // heavy+light pairing
  __shared__ __align__(16) u16 Ks[2][128][64];     // [k][d]
  __shared__ __align__(16) u16 Vt[2][64][128];     // [d][t] (s-perm 64-blocks)
  const int t = threadIdx.x, lane = t & 63, w = t >> 6;
  const int l15 = lane & 15, l4 = lane >> 4;
  const size_t base = (size_t)bh * Tq * Dq;
  const int qs0 = qb * 128 + w * 32;         // strip-0 base (strip1 = +16)

  // Q fragments (B-operand) per strip
  bf16x8 qf[2][2];
  {
    const u16* qp = qw + base + (size_t)(qs0 + l15) * Dq + l4 * 8;
    qf[0][0] = *(const bf16x8*)qp;
    qf[0][1] = *(const bf16x8*)(qp + 32);
    qf[1][0] = *(const bf16x8*)(qp + 16 * Dq);
    qf[1][1] = *(const bf16x8*)(qp + 16 * Dq + 32);
  }

  // staging lanes: K -> 8 rows x 8 chunks, V -> 4 rows x 16 chunks per GLD16
  const int kl_r = lane >> 3, kl_c = lane & 7;
  const int vl_r = lane >> 4, vl_c = lane & 15;
  const int vhb = vl_c >> 3, vgg = vl_c & 7;
  const u16* kbase = kw + base;
  const u16* vbase = vts + base;

#define STAGE(kv_, b_)                                                       \
  do {                                                                       \
    _Pragma("unroll") for (int i = 0; i < 4; i++) {                          \
      int r = i * 32 + w * 8 + kl_r;                                         \
      GLD16(kbase + (size_t)((kv_)*128 + r) * Dq + ((kl_c ^ (r & 7)) * 8),   \
            &Ks[b_][i * 32 + w * 8][0]);                                     \
    }                                                                        \
    _Pragma("unroll") for (int i = 0; i < 4; i++) {                          \
      int r = i * 16 + w * 4 + vl_r;                                         \
      GLD16(vbase + (size_t)r * Tq + (kv_)*128 + vhb * 64 +                  \
                ((vgg ^ (r & 7)) * 8),                                       \
            &Vt[b_][i * 16 + w * 4][0]);                                     \
    }                                                                        \
  } while (0)

  float m[2] = {-1e30f, -1e30f}, lsum[2] = {0.f, 0.f};
  f32x4 accO[2][4] = {};

  STAGE(0, 0);
  __syncthreads();

  for (int kv = 0; kv <= qb; kv++) {
    const int cur = kv & 1;
    if (kv < qb) STAGE(kv + 1, cur ^ 1);  // in flight across compute

    // active sub-tile bounds (wave-uniform; full tiles: 8 / 4)
    const int span = qs0 + 31 - kv * 128;              // >= 31 always
    const int ctmax = (span >= 127) ? 8 : ((span >> 4) + 1);
    const int hmax = (span >= 127) ? 4 : ((span >> 5) + 1);

    // swapped QK^T: sc[s][ct][r] = S[k = kv*128+ct*16+l4*4+r][q]
    f32x4 sc[2][8];
    __builtin_amdgcn_s_setprio(1);
#pragma unroll
    for (int ct = 0; ct < 8; ct++) {
      if (ct < ctmax) {
        const int kr = ct * 16 + l15, e = kr & 7;
        bf16x8 kf0 = *(const bf16x8*)&Ks[cur][kr][8 * (l4 ^ e)];
        bf16x8 kf1 = *(const bf16x8*)&Ks[cur][kr][8 * ((4 + l4) ^ e)];
        f32x4 z0 = {};
        z0 = mfma16(kf0, qf[0][0], z0); z0 = mfma16(kf1, qf[0][1], z0);
        sc[0][ct] = z0;
        f32x4 z1 = {};
        z1 = mfma16(kf0, qf[1][0], z1); z1 = mfma16(kf1, qf[1][1], z1);
        sc[1][ct] = z1;
      }
    }
    __builtin_amdgcn_s_setprio(0);

    if (kv == qb) {  // diagonal: per-element causal mask on active cts
#pragma unroll
      for (int s = 0; s < 2; s++) {
        const int q = qs0 + s * 16 + l15;
#pragma unroll
        for (int ct = 0; ct < 8; ct++) {
          if (ct < ctmax) {
#pragma unroll
            for (int r = 0; r < 4; r++) {
              int k = kv * 128 + ct * 16 + l4 * 4 + r;
              if (k > q) sc[s][ct][r] = -1e30f;
            }
          }
        }
      }
    }

    // per-strip online softmax (lane-local partials)
#pragma unroll
    for (int s = 0; s < 2; s++) {
      float pmax = -1e30f;
#pragma unroll
      for (int ct = 0; ct < 8; ct++)
        if (ct < ctmax) {
#pragma unroll
          for (int r = 0; r < 4; r++) pmax = fmaxf(pmax, sc[s][ct][r]);
        }

      if (__any(pmax > m[s] + 8.f)) {  // defer-max: rescale rarely
        pmax = fmaxf(pmax, __shfl_xor(pmax, 16));
        pmax = fmaxf(pmax, __shfl_xor(pmax, 32));
        float mn = fmaxf(m[s], pmax);
        float corr = exp2f(m[s] - mn);
        m[s] = mn;
        lsum[s] *= corr;
#pragma unroll
        for (int r = 0; r < 4; r++) {  // corr for q=l4*4+r at lane 20*l4+r
          float cb = __shfl(corr, (lane >> 4) * 20 + r);
#pragma unroll
          for (int dt = 0; dt < 4; dt++) accO[s][dt][r] *= cb;
        }
      }

      float psum = 0.f;
#pragma unroll
      for (int ct = 0; ct < 8; ct++)
        if (ct < ctmax) {
#pragma unroll
          for (int r = 0; r < 4; r++) {
            float p = exp2f(sc[s][ct][r] - m[s]);
            sc[s][ct][r] = p;
            psum += p;
          }
        }
      lsum[s] += psum;  // per-lane partial; reduced in epilogue
    }

    // PV per active 32-k half h: pa lane-local (rho-trick), vf shared
    __builtin_amdgcn_s_setprio(1);
#pragma unroll
    for (int h = 0; h < 4; h++) {
      if (h < hmax) {
        bf16x8 pa[2];
#pragma unroll
        for (int s = 0; s < 2; s++) {
          uint4v pu;
          pu[0] = cvt_pk_bf16(sc[s][2 * h][0], sc[s][2 * h][1]);
          pu[1] = cvt_pk_bf16(sc[s][2 * h][2], sc[s][2 * h][3]);
          pu[2] = cvt_pk_bf16(sc[s][2 * h + 1][0], sc[s][2 * h + 1][1]);
          pu[3] = cvt_pk_bf16(sc[s][2 * h + 1][2], sc[s][2 * h + 1][3]);
          pa[s] = __builtin_bit_cast(bf16x8, pu);
        }
#pragma unroll
        for (int dt = 0; dt < 4; dt++) {
          const int Rv = dt * 16 + l15, e = Rv & 7;
          bf16x8 vf = *(const bf16x8*)&Vt[cur][Rv]
              [(h >> 1) * 64 + 8 * ((((h & 1) * 4 + l4)) ^ e)];
          accO[0][dt] = mfma16(pa[0], vf, accO[0][dt]);
          accO[1][dt] = mfma16(pa[1], vf, accO[1][dt]);
        }
      }
    }
    __builtin_amdgcn_s_setprio(0);

    __syncthreads();  // drains gld (next buf ready) + guards dbuf rotation
  }
#undef STAGE

  // epilogue: reduce lsum across the 4 k-lanes, then normalize + store
  const int b = bh >> 4, hd = bh & 15;
#pragma unroll
  for (int s = 0; s < 2; s++) {
    float L = lsum[s];
    L += __shfl_xor(L, 16);
    L += __shfl_xor(L, 32);
    float inv = 1.0f / L;
#pragma unroll
    for (int r = 0; r < 4; r++) {
      float ib = __shfl(inv, (lane >> 4) * 20 + r);
      int tt = qs0 + s * 16 + l4 * 4 + r;
      size_t rowbase = ((size_t)(b * Tq + tt)) * Cq + hd * 64;
#pragma unroll
      for (int dt = 0; dt < 4; dt++)
        yw[rowbase + dt * 16 + l15] = f2bf(accO[s][dt][r] * ib);
    }
  }
}

// ---------------------------------------------------------------------------
// Kernel 3: out = y @ Wt_proj^T + b_proj (fp32 out). m97 structure.
// ---------------------------------------------------------------------------
__global__ __launch_bounds__(256) void proj_gemm(
    const u16* __restrict__ A, const u16* __restrict__ Bt,
    const float* __restrict__ bias, float* __restrict__ out) {
  const int K = 1024, N = 1024;
  __shared__ __align__(16) u16 As[128][32];
  __shared__ __align__(16) u16 Bs[128][32];
  const int m0 = blockIdx.x * 128, n0 = blockIdx.y * 128;
  const int t = threadIdx.x, lane = t & 63, w = t >> 6;
  const int wm = (w >> 1) * 64, wn = (w & 1) * 64;
  const int l15 = lane & 15, l4 = lane >> 4;
  const int lr = lane >> 2, lc = (lane & 3) * 8;
  f32x4 acc[4][4] = {};
  const u16* ga = A + (size_t)(m0 + w * 16 + lr) * K + lc;
  const u16* gb = Bt + (size_t)(n0 + w * 16 + lr) * K + lc;

  for (int kk = 0; kk < K; kk += 32) {
    __syncthreads();
    GLD16(ga + kk, &As[w * 16][0]);
    GLD16(ga + (size_t)64 * K + kk, &As[64 + w * 16][0]);
    GLD16(gb + kk, &Bs[w * 16][0]);
    GLD16(gb + (size_t)64 * K + kk, &Bs[64 + w * 16][0]);
    __syncthreads();
    bf16x8 af[4], bfr[4];
#pragma unroll
    for (int i = 0; i < 4; i++) {
      af[i] = *(const bf16x8*)&As[wm + i * 16 + l15][l4 * 8];
      bfr[i] = *(const bf16x8*)&Bs[wn + i * 16 + l15][l4 * 8];
    }
#pragma unroll
    for (int mi = 0; mi < 4; mi++)
#pragma unroll
      for (int ni = 0; ni < 4; ni++)
        acc[mi][ni] = mfma16(af[mi], bfr[ni], acc[mi][ni]);
  }
#pragma unroll
  for (int mi = 0; mi < 4; mi++) {
#pragma unroll
    for (int ni = 0; ni < 4; ni++) {
#pragma unroll
      for (int r = 0; r < 4; r++) {
        int row = m0 + wm + mi * 16 + l4 * 4 + r;
        int col = n0 + wn + ni * 16 + l15;
        out[(size_t)row * N + col] = acc[mi][ni][r] + bias[col];
      }
    }
  }
}

// ---------------------------------------------------------------------------
// Workspace (u16 elems): qw 4M | kw 4M | vw 4M (-> yw after transpose_v) |
// xb 4M (-> vts after qkv_gemm) | wt 3M. Total 38 MB.
// ---------------------------------------------------------------------------
extern "C" void kernel_launch(void* const* d_in, const int* in_sizes, int n_in,
                              void* d_out, int out_size, void* d_ws, size_t ws_size,
                              hipStream_t stream) {
  const float* x = (const float*)d_in[0];
  const float* W_qkv = (const float*)d_in[1];
  const float* b_qkv = (const float*)d_in[2];
  const float* W_proj = (const float*)d_in[3];
  const float* b_proj = (const float*)d_in[4];
  float* out = (float*)d_out;

  const size_t qkv_elems = (size_t)Bq * Hq * Tq * Dq;  // 4M
  u16* qw = (u16*)d_ws;
  u16* kw = qw + qkv_elems;
  u16* vw = kw + qkv_elems;
  u16* xb = vw + qkv_elems;
  u16* wt = xb + (size_t)Mq * Cq;
  u16* vts = xb;  // xb dead after qkv_gemm
  u16* yw = vw;   // vw dead after transpose_v

  convert_x<<<dim3((Mq * Cq) / (256 * 8)), 256, 0, stream>>>(x, xb);
  transpose_w<<<dim3(Cq / 64, 3 * Cq / 64), 256, 0, stream>>>(W_qkv, wt, Cq, 3 * Cq);
  qkv_gemm<<<dim3(Mq / 128, 3 * Cq / 128), 256, 0, stream>>>(xb, wt, b_qkv, qw, kw, vw);
  transpose_v<<<dim3(Tq / 64, Bq * Hq), 256, 0, stream>>>(vw, vts);
  transpose_w<<<dim3(Cq / 64, Cq / 64), 256, 0, stream>>>(W_proj, wt, Cq, Cq);
  attn<<<dim3(Bq * Hq, Tq / 128), 256, 0, stream>>>(qw, kw, vts, yw);
  proj_gemm<<<dim3(Mq / 128, Cq / 128), 256, 0, stream>>>(yw, wt, b_proj, out);
}